// Round 13
// baseline (243.179 us; speedup 1.0000x reference)
//
#include <hip/hip_runtime.h>
#include <hip/hip_cooperative_groups.h>
#include <hip/hip_fp16.h>

namespace cg = cooperative_groups;

// DenseGATv2: B=4, N=1024, D=128, H=8, QKV=16
// in: h (B,N,D) f32 | same_cluster (B,N,N) int | Wa (2D+1,H) f32 | Wv (D,H*QKV) f32
//     Wo (H*QKV,D) f32 | local_only int scalar
// out: (B,N,D) f32

#define NEG_SLOPE 0.15f
#define LOG2E 1.442695040888963f
#define B_ 4
#define N_ 1024
#define D_ 128
#define H_ 8
#define QKV_ 16
#define BN_ (B_ * N_)
#define GRID_ 512

typedef _Float16 half8 __attribute__((ext_vector_type(8)));
typedef float f32x4 __attribute__((ext_vector_type(4)));

// ws layout (bytes):
//  SIt f32 [H*BN]      @0         131072
//  SJt f32 [H*BN]      @131072    131072
//  ATT f32 [BN*128]    @262144   2097152
//  VT  f16 [B*H*16*N]  @2359296  1048576
//  EM  u64 [BN*16]     @3407872   524288
#define WS_BYTES ((size_t)3932160)

// ---------------------------------------------------------------------------
// One cooperative kernel, three phases separated by grid.sync():
//  P: prep (8 rows/block): VT=(h@Wv)^T f16, SIt/SJt=(h@Wa_i|j)*LOG2E,
//     EM = edge bitmask (1 ballot per 64 j).
//  A: attention (4 tiles/block): MFMA PV, scores from SIt/SJt/EM.
//  O: out = ATT @ Wo (8 rows/block).
// grid = 512 blocks x 256 thr = 2 blocks/CU -> co-residency guaranteed.
// ---------------------------------------------------------------------------
__global__ __launch_bounds__(256, 2) void fused_kernel(
    const float* __restrict__ h, const int* __restrict__ edge,
    const float* __restrict__ Wa, const float* __restrict__ Wv,
    const float* __restrict__ Wo, const int* __restrict__ local_only,
    float* __restrict__ SIt, float* __restrict__ SJt,
    float* __restrict__ ATT, _Float16* __restrict__ VT,
    unsigned long long* __restrict__ EM, float* __restrict__ out)
{
    cg::grid_group grid = cg::this_grid();
    __shared__ float hl[8][128];
    __shared__ float olds[4][16][17];
    __shared__ float denl[4][16];

    const int t   = threadIdx.x;
    const int bid = blockIdx.x;
    const int w   = t >> 6;         // wave id 0..3
    const int l   = t & 63;         // lane

    // ================= phase P: prep (8 rows/block) =================
    {
        const int R0 = bid * 8;
        {   // stage 8 rows of h
            const int f = t * 4;
            *(float4*)(&hl[0][0] + f) = *(const float4*)(h + (size_t)R0 * 128 + f);
        }
        __syncthreads();

        // pass A: VT = (h@Wv)^T in f16, layout (B,H,d0..15,N)
        const int cq = t & 31, rq = t >> 5;
        const int c4 = cq * 4;
        float a0 = 0.f, a1 = 0.f, a2 = 0.f, a3 = 0.f;
        #pragma unroll 8
        for (int k = 0; k < 128; ++k) {
            const float4 wv = *(const float4*)(Wv + k * 128 + c4);
            const float a = hl[rq][k];
            a0 += a * wv.x; a1 += a * wv.y; a2 += a * wv.z; a3 += a * wv.w;
        }
        {
            const int R = R0 + rq, b = R >> 10, n = R & 1023;
            const int head = cq >> 2, dd = (cq & 3) * 4;
            _Float16* vt = VT + ((size_t)(b * H_ + head) * 16 + dd) * N_ + n;
            vt[0]      = (_Float16)a0;
            vt[N_]     = (_Float16)a1;
            vt[2 * N_] = (_Float16)a2;
            vt[3 * N_] = (_Float16)a3;
        }

        // pass B: SIt/SJt (pre-scaled by LOG2E for exp2)
        {
            const int task = t >> 1, half = t & 1;
            const int row = task >> 4, which = (task >> 3) & 1, hh = task & 7;
            const float* wcol = Wa + which * 128 * H_ + hh;
            float s = 0.f;
            #pragma unroll 8
            for (int kk = 0; kk < 64; ++kk) {
                const int k = half * 64 + kk;
                s += hl[row][k] * wcol[k * H_];
            }
            s += __shfl_xor(s, 1, 64);
            if (!half) (which ? SJt : SIt)[hh * BN_ + R0 + row] = s * LOG2E;
        }

        // pass C: edge bitmask. wave w packs rows {R0+2w, R0+2w+1}:
        // lane l tests j = s*64+l; ballot -> u64; little-endian byte k of the
        // word = bits for j = s*64+8k..+7 (attn reads single bytes).
        #pragma unroll
        for (int rr = 0; rr < 2; ++rr) {
            const int R = R0 + w * 2 + rr;
            const int* erow = edge + (size_t)R * N_;
            #pragma unroll 4
            for (int s = 0; s < 16; ++s) {
                const unsigned long long mk = __ballot(erow[s * 64 + l] != 0);
                if (l == 0) EM[(size_t)R * 16 + s] = mk;
            }
        }
    }

    grid.sync();

    // ================= phase A: attention (4 tiles/block) =================
    // tile = (b, hh, i0/16); wave w owns j-quarter [w*256,(w+1)*256).
    // P computed in the A-fragment layout of mfma_f32_16x16x32_f16
    // (lane: row=l&15, k=8*(l>>4)+u); B-frag = 16B load from VT[d=l&15][j].
    const int lo = local_only[0];
    const unsigned char* EMb = (const unsigned char*)EM;
    const int m  = l & 15;
    const int kq = l >> 4;
    for (int q = 0; q < 4; ++q) {
        const int tile = bid + GRID_ * q;
        const int b   = tile >> 9;
        const int hh  = (tile >> 6) & 7;
        const int i0  = (tile & 63) * 16;
        const int bn0 = b * N_;

        const float we    = Wa[2 * D_ * H_ + hh] * LOG2E;
        const float sim   = SIt[hh * BN_ + bn0 + i0 + m];
        const float simwe = sim + we;
        const float simNE = lo ? -1e6f : sim;
        const float*    sjrow = SJt + hh * BN_ + bn0;
        const _Float16* vrow  = VT + ((size_t)(b * H_ + hh) * 16 + m) * N_;
        const size_t    eb0   = (size_t)(bn0 + i0 + m) * 128 + w * 32 + kq;

        f32x4 acc = {0.f, 0.f, 0.f, 0.f};
        float dsum = 0.f;
        const int wj0 = w * 256;
        #pragma unroll 2
        for (int c = 0; c < 8; ++c) {
            const int jb = wj0 + c * 32 + kq * 8;       // lane's 8 j's
            const float4 sjA = *(const float4*)(sjrow + jb);
            const float4 sjB = *(const float4*)(sjrow + jb + 4);
            const half8  bf  = *(const half8*)(vrow + jb);
            const int    eb  = EMb[eb0 + c * 4];        // 8 edge bits
            const float sj[8] = {sjA.x, sjA.y, sjA.z, sjA.w,
                                 sjB.x, sjB.y, sjB.z, sjB.w};
            half8 av;
            #pragma unroll
            for (int u = 0; u < 8; ++u) {
                const float x  = (((eb >> u) & 1) ? simwe : simNE) + sj[u];
                const float sc = fmaxf(x, NEG_SLOPE * x);   // leaky_relu
                const float p  = exp2f(sc);
                dsum += p;
                av[u] = (_Float16)p;
            }
            acc = __builtin_amdgcn_mfma_f32_16x16x32_f16(av, bf, acc, 0, 0, 0);
        }
        dsum += __shfl_xor(dsum, 16, 64);
        dsum += __shfl_xor(dsum, 32, 64);

        #pragma unroll
        for (int reg = 0; reg < 4; ++reg)
            olds[w][kq * 4 + reg][m] = acc[reg];  // C/D: col=l&15, row=4*kq+reg
        if (l < 16) denl[w][l] = dsum;
        __syncthreads();
        {
            const int i = t >> 4, d = t & 15;
            const float o   = olds[0][i][d] + olds[1][i][d]
                            + olds[2][i][d] + olds[3][i][d];
            const float den = denl[0][i] + denl[1][i] + denl[2][i] + denl[3][i];
            ATT[(size_t)(bn0 + i0 + i) * 128 + hh * 16 + d] = o / den;
        }
        __syncthreads();   // olds/denl reused by next tile
    }

    grid.sync();

    // ================= phase O: out = ATT @ Wo (8 rows/block) =================
    {
        const int R0 = bid * 8;
        {
            const int f = t * 4;
            *(float4*)(&hl[0][0] + f) = *(const float4*)(ATT + (size_t)R0 * 128 + f);
        }
        __syncthreads();
        const int cq = t & 31, rq = t >> 5;
        const int c4 = cq * 4;
        float a0 = 0.f, a1 = 0.f, a2 = 0.f, a3 = 0.f;
        #pragma unroll 8
        for (int k = 0; k < 128; ++k) {
            const float4 wv = *(const float4*)(Wo + k * 128 + c4);
            const float a = hl[rq][k];
            a0 += a * wv.x; a1 += a * wv.y; a2 += a * wv.z; a3 += a * wv.w;
        }
        float4 o; o.x = a0; o.y = a1; o.z = a2; o.w = a3;
        *(float4*)(out + (size_t)(R0 + rq) * 128 + c4) = o;
    }
}

// ---------------------------------------------------------------------------
extern "C" void kernel_launch(void* const* d_in, const int* in_sizes, int n_in,
                              void* d_out, int out_size, void* d_ws, size_t ws_size,
                              hipStream_t stream) {
    const float* h    = (const float*)d_in[0];
    const int*   edge = (const int*)d_in[1];
    const float* Wa   = (const float*)d_in[2];
    const float* Wv   = (const float*)d_in[3];
    const float* Wo   = (const float*)d_in[4];
    const int*   lo   = (const int*)d_in[5];
    float*       out  = (float*)d_out;

    // Zero the used ws extent every call (R8 evidence: ws-poison sensitivity;
    // R9 confirmed this memset fixes it). ~3.9 MB, graph-capture-legal.
    hipMemsetAsync(d_ws, 0, WS_BYTES, stream);

    char* ws = (char*)d_ws;
    float*              SIt = (float*)(ws);
    float*              SJt = (float*)(ws + 131072);
    float*              ATT = (float*)(ws + 262144);
    _Float16*           VT  = (_Float16*)(ws + 2359296);
    unsigned long long* EM  = (unsigned long long*)(ws + 3407872);

    void* args[] = { (void*)&h, (void*)&edge, (void*)&Wa, (void*)&Wv,
                     (void*)&Wo, (void*)&lo, (void*)&SIt, (void*)&SJt,
                     (void*)&ATT, (void*)&VT, (void*)&EM, (void*)&out };
    hipLaunchCooperativeKernel((void*)fused_kernel, dim3(GRID_), dim3(256),
                               args, 0, stream);
}

// Round 14
// 128.570 us; speedup vs baseline: 1.8914x; 1.8914x over previous
//
#include <hip/hip_runtime.h>
#include <hip/hip_fp16.h>

// DenseGATv2: B=4, N=1024, D=128, H=8, QKV=16
// in: h (B,N,D) f32 | same_cluster (B,N,N) int | Wa (2D+1,H) f32 | Wv (D,H*QKV) f32
//     Wo (H*QKV,D) f32 | local_only int scalar
// out: (B,N,D) f32

#define NEG_SLOPE 0.15f
#define LOG2E 1.442695040888963f
#define B_ 4
#define N_ 1024
#define D_ 128
#define H_ 8
#define QKV_ 16
#define BN_ (B_ * N_)

typedef _Float16 half8 __attribute__((ext_vector_type(8)));
typedef float f32x4 __attribute__((ext_vector_type(4)));

// ws layout (bytes):
//  SIt f32 [H*BN]      @0         131072
//  SJt f32 [H*BN]      @131072    131072
//  ATT f32 [BN*128]    @262144   2097152
//  VT  f16 [B*H*16*N]  @2359296  1048576
//  EM  u64 [BN*16]     @3407872   524288
#define WS_BYTES ((size_t)3932160)

// ---------------------------------------------------------------------------
// Kernel 1: prep, 8 rows/block, 512 blocks.
//  pass A: VT = (h@Wv)^T f16, layout (B,H,d0..15,N)  (MFMA B-fragments)
//  pass B: SIt/SJt = (h@Wa_i|j) * LOG2E, layout (H,B*N)
//  pass C: EM = edge bitmask, 1 ballot per 64 j (attn reads 1 byte / 8 j)
// ---------------------------------------------------------------------------
__global__ __launch_bounds__(256) void prep_kernel(
    const float* __restrict__ h, const int* __restrict__ edge,
    const float* __restrict__ Wa, const float* __restrict__ Wv,
    float* __restrict__ SIt, float* __restrict__ SJt,
    _Float16* __restrict__ VT, unsigned long long* __restrict__ EM)
{
    __shared__ float hl[8][128];
    const int t  = threadIdx.x;
    const int w  = t >> 6;
    const int l  = t & 63;
    const int R0 = blockIdx.x * 8;

    {   // stage 8 rows of h (1 float4/thread, coalesced)
        const int f = t * 4;
        *(float4*)(&hl[0][0] + f) = *(const float4*)(h + (size_t)R0 * 128 + f);
    }
    __syncthreads();

    // pass A: thread (cq, rq): row rq, cols cq*4..+3 of h@Wv
    const int cq = t & 31, rq = t >> 5;
    const int c4 = cq * 4;
    float a0 = 0.f, a1 = 0.f, a2 = 0.f, a3 = 0.f;
    #pragma unroll 8
    for (int k = 0; k < 128; ++k) {
        const float4 wv = *(const float4*)(Wv + k * 128 + c4);
        const float a = hl[rq][k];
        a0 += a * wv.x; a1 += a * wv.y; a2 += a * wv.z; a3 += a * wv.w;
    }
    {
        const int R = R0 + rq, b = R >> 10, n = R & 1023;
        const int head = cq >> 2, dd = (cq & 3) * 4;
        _Float16* vt = VT + ((size_t)(b * H_ + head) * 16 + dd) * N_ + n;
        vt[0]      = (_Float16)a0;
        vt[N_]     = (_Float16)a1;
        vt[2 * N_] = (_Float16)a2;
        vt[3 * N_] = (_Float16)a3;
    }

    // pass B: task = (row, which, hh), 2-way k-split; store s * LOG2E
    {
        const int task = t >> 1, half = t & 1;
        const int row = task >> 4, which = (task >> 3) & 1, hh = task & 7;
        const float* wcol = Wa + which * 128 * H_ + hh;
        float s = 0.f;
        #pragma unroll 8
        for (int kk = 0; kk < 64; ++kk) {
            const int k = half * 64 + kk;
            s += hl[row][k] * wcol[k * H_];
        }
        s += __shfl_xor(s, 1, 64);
        if (!half) (which ? SJt : SIt)[hh * BN_ + R0 + row] = s * LOG2E;
    }

    // pass C: edge bitmask. wave w packs rows {R0+2w, R0+2w+1}; lane l tests
    // j = s*64+l; ballot -> u64 word s. Little-endian byte k of word s holds
    // bits for j = s*64+8k..+7, i.e. row-relative byte index = j>>3.
    #pragma unroll
    for (int rr = 0; rr < 2; ++rr) {
        const int R = R0 + w * 2 + rr;
        const int* erow = edge + (size_t)R * N_;
        #pragma unroll 4
        for (int s = 0; s < 16; ++s) {
            const unsigned long long mk = __ballot(erow[s * 64 + l] != 0);
            if (l == 0) EM[(size_t)R * 16 + s] = mk;
        }
    }
}

// ---------------------------------------------------------------------------
// Kernel 2: fused attention with MFMA PV + edge bitmask.
// Block = 16 i-rows x head x batch; wave w owns j-quarter [w*256,(w+1)*256).
// P computed directly in the A-fragment layout of mfma_f32_16x16x32_f16
// (lane: row=l&15, k=8*(l>>4)+u); B-frag = one 16B load from VT[d=l&15][j].
// Denominator via a second MFMA with B = ones (row-sum on the matrix pipe,
// freeing ~64 VALU adds + 2 shuffles per lane). Epilogue: 4-wave LDS reduce.
// grid = (N/16,H,B) = 2048 blocks.
// ---------------------------------------------------------------------------
__global__ __launch_bounds__(256) void attn_kernel(
    const float* __restrict__ SIt, const float* __restrict__ SJt,
    const _Float16* __restrict__ VT, const unsigned long long* __restrict__ EM,
    const float* __restrict__ Wa, const int* __restrict__ local_only,
    float* __restrict__ ATT)
{
    const int t  = threadIdx.x;
    const int w  = t >> 6;          // wave id 0..3 (j-quarter)
    const int l  = t & 63;          // lane
    const int m  = l & 15;          // A row (i) / B col (d)
    const int kq = l >> 4;          // k-quad within 32-j chunk
    const int hh = blockIdx.y;
    const int b  = blockIdx.z;
    const int i0 = blockIdx.x * 16;
    const int bn0 = b * N_;

    const float we = Wa[2 * D_ * H_ + hh] * LOG2E;
    const int   lo = local_only[0];

    const float sim   = SIt[hh * BN_ + bn0 + i0 + m];   // pre-scaled by LOG2E
    const float simwe = sim + we;
    const float simNE = lo ? -1e6f : sim;               // local_only: p -> 0

    const float*         sjrow = SJt + hh * BN_ + bn0;
    const _Float16*      vrow  = VT + ((size_t)(b * H_ + hh) * 16 + m) * N_;
    const unsigned char* EMb   = (const unsigned char*)EM;
    const size_t         eb0   = (size_t)(bn0 + i0 + m) * 128 + w * 32 + kq;

    f32x4 acc  = {0.f, 0.f, 0.f, 0.f};
    f32x4 acc2 = {0.f, 0.f, 0.f, 0.f};   // row-sum accumulator (denominator)
    const half8 ones = {(_Float16)1.f, (_Float16)1.f, (_Float16)1.f, (_Float16)1.f,
                        (_Float16)1.f, (_Float16)1.f, (_Float16)1.f, (_Float16)1.f};

    const int wj0 = w * 256;
    #pragma unroll 2
    for (int c = 0; c < 8; ++c) {
        const int jb = wj0 + c * 32 + kq * 8;           // lane's 8 j's
        const float4 sjA = *(const float4*)(sjrow + jb);
        const float4 sjB = *(const float4*)(sjrow + jb + 4);
        const half8  bf  = *(const half8*)(vrow + jb);  // B-frag: V[j][d=m]
        const int    eb  = EMb[eb0 + c * 4];            // 8 edge bits (j=jb..+7)

        const float sj[8] = {sjA.x, sjA.y, sjA.z, sjA.w,
                             sjB.x, sjB.y, sjB.z, sjB.w};
        half8 av;
        #pragma unroll
        for (int u = 0; u < 8; ++u) {
            const float x  = (((eb >> u) & 1) ? simwe : simNE) + sj[u];
            const float sc = fmaxf(x, NEG_SLOPE * x);   // leaky_relu (log2-dom)
            av[u] = (_Float16)exp2f(sc);                // A-frag element
        }
        acc  = __builtin_amdgcn_mfma_f32_16x16x32_f16(av, bf,   acc,  0, 0, 0);
        acc2 = __builtin_amdgcn_mfma_f32_16x16x32_f16(av, ones, acc2, 0, 0, 0);
    }

    __shared__ float olds[4][16][17];   // [wave][i][d] (+1 pad)
    __shared__ float denl[4][16];
    #pragma unroll
    for (int reg = 0; reg < 4; ++reg)
        olds[w][kq * 4 + reg][m] = acc[reg];   // C/D: col=l&15, row=4*kq+reg
    if (m == 0) {                              // lanes 0,16,32,48: rows 4kq+reg
        #pragma unroll
        for (int reg = 0; reg < 4; ++reg)
            denl[w][kq * 4 + reg] = acc2[reg];
    }
    __syncthreads();

    {   // cross-wave reduce + store: thread t -> (i = t>>4, d = t&15)
        const int i = t >> 4, d = t & 15;
        const float o   = olds[0][i][d] + olds[1][i][d]
                        + olds[2][i][d] + olds[3][i][d];
        const float den = denl[0][i] + denl[1][i] + denl[2][i] + denl[3][i];
        ATT[(size_t)(bn0 + i0 + i) * 128 + hh * 16 + d] = o / den;
    }
}

// ---------------------------------------------------------------------------
// Kernel 3: out = ATT (B*N,128) @ Wo (128,128). 8 rows/block, 512 blocks.
// ---------------------------------------------------------------------------
__global__ __launch_bounds__(256) void out_kernel(
    const float* __restrict__ ATT, const float* __restrict__ Wo,
    float* __restrict__ out)
{
    __shared__ float al[8][128];
    const int t  = threadIdx.x;
    const int R0 = blockIdx.x * 8;
    {
        const int f = t * 4;
        *(float4*)(&al[0][0] + f) = *(const float4*)(ATT + (size_t)R0 * 128 + f);
    }
    __syncthreads();

    const int cq = t & 31, rq = t >> 5;
    const int c4 = cq * 4;
    float a0 = 0.f, a1 = 0.f, a2 = 0.f, a3 = 0.f;
    #pragma unroll 8
    for (int k = 0; k < 128; ++k) {
        const float4 wv = *(const float4*)(Wo + k * 128 + c4);
        const float a = al[rq][k];
        a0 += a * wv.x; a1 += a * wv.y; a2 += a * wv.z; a3 += a * wv.w;
    }
    float4 o; o.x = a0; o.y = a1; o.z = a2; o.w = a3;
    *(float4*)(out + (size_t)(R0 + rq) * 128 + c4) = o;
}

// ---------------------------------------------------------------------------
extern "C" void kernel_launch(void* const* d_in, const int* in_sizes, int n_in,
                              void* d_out, int out_size, void* d_ws, size_t ws_size,
                              hipStream_t stream) {
    const float* h    = (const float*)d_in[0];
    const int*   edge = (const int*)d_in[1];
    const float* Wa   = (const float*)d_in[2];
    const float* Wv   = (const float*)d_in[3];
    const float* Wo   = (const float*)d_in[4];
    const int*   lo   = (const int*)d_in[5];
    float*       out  = (float*)d_out;

    // Zero the used ws extent every call (R8 evidence: ws-poison sensitivity;
    // R9/R12 confirmed this memset fixes it). ~3.9 MB, graph-capture-legal.
    hipMemsetAsync(d_ws, 0, WS_BYTES, stream);

    char* ws = (char*)d_ws;
    float*              SIt = (float*)(ws);
    float*              SJt = (float*)(ws + 131072);
    float*              ATT = (float*)(ws + 262144);
    _Float16*           VT  = (_Float16*)(ws + 2359296);
    unsigned long long* EM  = (unsigned long long*)(ws + 3407872);

    prep_kernel<<<BN_ / 8, 256, 0, stream>>>(h, edge, Wa, Wv, SIt, SJt, VT, EM);
    attn_kernel<<<dim3(N_ / 16, H_, B_), 256, 0, stream>>>(SIt, SJt, VT, EM, Wa, lo, ATT);
    out_kernel<<<BN_ / 8, 256, 0, stream>>>(ATT, Wo, out);
}